// Round 7
// baseline (148.497 us; speedup 1.0000x reference)
//
#include <hip/hip_runtime.h>

// Problem constants
#define NB 2
#define CC 512
#define NN 2304
#define NH 8
#define DD 16
#define TT 128          // NH*DD
#define O3 384          // 3*TT

typedef __attribute__((ext_vector_type(4))) float f32x4;
typedef __attribute__((ext_vector_type(8))) __bf16 bf16x8;
typedef __attribute__((ext_vector_type(4))) __bf16 bf16x4;
typedef __attribute__((ext_vector_type(4))) _Float16 f16x4;
typedef __attribute__((ext_vector_type(2))) __fp16 hf16x2;   // cvt_pkrtz return type

union hf2pair {                       // bit-reinterpret 2x(__fp16 x2) -> f16x4
    hf16x2 h[2];
    f16x4  v;
};

// workspace layout (bytes) — xT/wqb/wob deleted (R7: transpose fused into k1
// via LDS; weights read fp32-direct with in-register cvt).
#define OFF_Q  0u               // 2*8*2304*16*2 = 1,179,648
#define OFF_K  1179648u
#define OFF_VT 2359296u
#define OFF_AO 3538944u         // 2*2304*128*2 = 1,179,648 -> 4,718,592

// ---------------------------------------------------------------------------
// Kernel 1: QKV GEMM  qkvT[n,o] = sum_c x[c,n] * W[o,c]  (per batch),
// fused per-head L2 norm of q,k.
// R7: k0 deleted. Each block stages its x-tile [512c][64n] fp32 -> LDS
// As[64n][520c] bf16 (coalesced float4 reads along n; transpose via LDS;
// row pad 520 keeps rows 16B-aligned). A-frags then come from ds_read_b128
// (same as the verified bf16 path). W read fp32-direct + in-register cvt
// (the cheap half of R4). Fragment values bit-identical to the k0 path.
// Outputs: Q,K: [bh][n][16] f16 ;  VT: [bh][16][n] f16
// ---------------------------------------------------------------------------
__global__ __launch_bounds__(256) void k1_qkv(
    const float* __restrict__ x, const float* __restrict__ wqkv,
    _Float16* __restrict__ Q, _Float16* __restrict__ K, _Float16* __restrict__ VT)
{
    __shared__ __bf16 As[64][520];     // 66,560 B -> 2 blocks/CU
    int ob = blockIdx.x, nt = blockIdx.y, b = blockIdx.z;
    int tid = threadIdx.x;
    int lane = tid & 63, wave = tid >> 6;
    int quad = lane >> 4, col = lane & 15;
    int n0 = nt * 64;
    int o0 = ob * 64;

    // ---- stage x[b][c][n0..n0+63] -> As[n][c] (bf16, transposed) ----
    {
        int cb = tid >> 4;             // 0..15
        int nq = (tid & 15) * 4;       // 0,4,..,60
#pragma unroll
        for (int it = 0; it < 32; ++it) {
            int c = it * 16 + cb;
            f32x4 v = *(const f32x4*)(x + ((size_t)b * CC + c) * NN + n0 + nq);
            As[nq + 0][c] = (__bf16)v[0];
            As[nq + 1][c] = (__bf16)v[1];
            As[nq + 2][c] = (__bf16)v[2];
            As[nq + 3][c] = (__bf16)v[3];
        }
    }
    __syncthreads();

    f32x4 acc0 = {0.f,0.f,0.f,0.f}, acc1 = {0.f,0.f,0.f,0.f};
    f32x4 acc2 = {0.f,0.f,0.f,0.f}, acc3 = {0.f,0.f,0.f,0.f};

    int nrow = wave * 16 + col;        // A row in tile (wave owns 16 rows)
    const float* w0p = wqkv + (size_t)(o0 + col) * CC + quad * 8;
    const float* w1p = w0p + 16 * CC;
    const float* w2p = w0p + 32 * CC;
    const float* w3p = w0p + 48 * CC;

    // prefetch W ks=0 (fp32)
    f32x4 cw0a = *(const f32x4*)(w0p),     cw0b = *(const f32x4*)(w0p + 4);
    f32x4 cw1a = *(const f32x4*)(w1p),     cw1b = *(const f32x4*)(w1p + 4);
    f32x4 cw2a = *(const f32x4*)(w2p),     cw2b = *(const f32x4*)(w2p + 4);
    f32x4 cw3a = *(const f32x4*)(w3p),     cw3b = *(const f32x4*)(w3p + 4);

#pragma unroll
    for (int ks = 0; ks < 16; ks++) {
        f32x4 nw0a, nw0b, nw1a, nw1b, nw2a, nw2b, nw3a, nw3b;
        if (ks < 15) {
            nw0a = *(const f32x4*)(w0p + (ks + 1) * 32);
            nw0b = *(const f32x4*)(w0p + (ks + 1) * 32 + 4);
            nw1a = *(const f32x4*)(w1p + (ks + 1) * 32);
            nw1b = *(const f32x4*)(w1p + (ks + 1) * 32 + 4);
            nw2a = *(const f32x4*)(w2p + (ks + 1) * 32);
            nw2b = *(const f32x4*)(w2p + (ks + 1) * 32 + 4);
            nw3a = *(const f32x4*)(w3p + (ks + 1) * 32);
            nw3b = *(const f32x4*)(w3p + (ks + 1) * 32 + 4);
        }
        bf16x8 a = *(const bf16x8*)(&As[nrow][quad * 8 + ks * 32]);
        bf16x8 wf0, wf1, wf2, wf3;
#pragma unroll
        for (int j = 0; j < 4; j++) {
            wf0[j] = (__bf16)cw0a[j]; wf0[j + 4] = (__bf16)cw0b[j];
            wf1[j] = (__bf16)cw1a[j]; wf1[j + 4] = (__bf16)cw1b[j];
            wf2[j] = (__bf16)cw2a[j]; wf2[j + 4] = (__bf16)cw2b[j];
            wf3[j] = (__bf16)cw3a[j]; wf3[j + 4] = (__bf16)cw3b[j];
        }
        acc0 = __builtin_amdgcn_mfma_f32_16x16x32_bf16(a, wf0, acc0, 0, 0, 0);
        acc1 = __builtin_amdgcn_mfma_f32_16x16x32_bf16(a, wf1, acc1, 0, 0, 0);
        acc2 = __builtin_amdgcn_mfma_f32_16x16x32_bf16(a, wf2, acc2, 0, 0, 0);
        acc3 = __builtin_amdgcn_mfma_f32_16x16x32_bf16(a, wf3, acc3, 0, 0, 0);
        cw0a = nw0a; cw0b = nw0b; cw1a = nw1a; cw1b = nw1b;
        cw2a = nw2a; cw2b = nw2b; cw3a = nw3a; cw3b = nw3b;
    }

#pragma unroll
    for (int s = 0; s < 4; s++) {
        int oc = o0 + s * 16 + col;
        int d = oc & 15, h = (oc >> 4) & 7, kind = oc >> 7;  // 0=q 1=k 2=v
        f32x4 v = (s == 0) ? acc0 : (s == 1) ? acc1 : (s == 2) ? acc2 : acc3;
        if (kind < 2) {
            float ss0 = v[0] * v[0], ss1 = v[1] * v[1], ss2 = v[2] * v[2], ss3 = v[3] * v[3];
#pragma unroll
            for (int m = 1; m < 16; m <<= 1) {
                ss0 += __shfl_xor(ss0, m);
                ss1 += __shfl_xor(ss1, m);
                ss2 += __shfl_xor(ss2, m);
                ss3 += __shfl_xor(ss3, m);
            }
            v[0] *= 1.0f / fmaxf(sqrtf(ss0), 1e-12f);
            v[1] *= 1.0f / fmaxf(sqrtf(ss1), 1e-12f);
            v[2] *= 1.0f / fmaxf(sqrtf(ss2), 1e-12f);
            v[3] *= 1.0f / fmaxf(sqrtf(ss3), 1e-12f);
            _Float16* dst = (kind == 0 ? Q : K) + (size_t)(b * NH + h) * NN * DD;
#pragma unroll
            for (int r = 0; r < 4; r++) {
                int n = n0 + wave * 16 + quad * 4 + r;
                dst[(size_t)n * DD + d] = (_Float16)v[r];
            }
        } else {
            f16x4 pk;
#pragma unroll
            for (int r = 0; r < 4; r++) pk[r] = (_Float16)v[r];
            int n = n0 + wave * 16 + quad * 4;
            *(f16x4*)(VT + (size_t)((b * NH + h) * DD + d) * NN + n) = pk;
        }
    }
}

// ---------------------------------------------------------------------------
// Kernel 2: attention — transpose-free flash, 8 waves x 288 keys, LDS combine.
// (Byte-identical to verified R6.) temperature*log2e folded into Q frags;
// packed v_cvt_pkrtz for P f32->f16; l-sum via ones-A-fragment MFMA.
// Output: AO[b][n][t=h*16+d] bf16.
// ---------------------------------------------------------------------------
__global__ __launch_bounds__(512) void k2_attn(
    const _Float16* __restrict__ Q, const _Float16* __restrict__ K,
    const _Float16* __restrict__ VT, const float* __restrict__ temp,
    __bf16* __restrict__ AO)
{
    __shared__ float Osh[8][16][64];   // [wave][d][q]
    __shared__ float Lsh[8][64];       // [wave][q]

    int qt = blockIdx.x, bh = blockIdx.y;
    int lane = threadIdx.x & 63, wave = threadIdx.x >> 6;
    int quad = lane >> 4, col = lane & 15;
    int kbase = wave * 288;               // 8 waves x 288 keys = full 2304
    int qbase = qt * 64;

    const _Float16* Qb = Q + (size_t)bh * NN * DD;
    float tl2 = temp[bh & 7] * 1.4426950408889634f;   // exp(x)=2^(x*log2e)
    _Float16 tl2h = (_Float16)tl2;

    f16x4 qf0 = *(const f16x4*)(Qb + (size_t)(qbase +  0 + col) * DD + quad * 4);
    f16x4 qf1 = *(const f16x4*)(Qb + (size_t)(qbase + 16 + col) * DD + quad * 4);
    f16x4 qf2 = *(const f16x4*)(Qb + (size_t)(qbase + 32 + col) * DD + quad * 4);
    f16x4 qf3 = *(const f16x4*)(Qb + (size_t)(qbase + 48 + col) * DD + quad * 4);
#pragma unroll
    for (int j = 0; j < 4; j++) {      // fold temperature*log2e into Q
        qf0[j] *= tl2h; qf1[j] *= tl2h; qf2[j] *= tl2h; qf3[j] *= tl2h;
    }
    const f16x4 onesf = {(_Float16)1.f, (_Float16)1.f, (_Float16)1.f, (_Float16)1.f};

    f32x4 oa0 = {0.f,0.f,0.f,0.f}, oa1 = {0.f,0.f,0.f,0.f};
    f32x4 oa2 = {0.f,0.f,0.f,0.f}, oa3 = {0.f,0.f,0.f,0.f};
    f32x4 lc0 = {0.f,0.f,0.f,0.f}, lc1 = {0.f,0.f,0.f,0.f};
    f32x4 lc2 = {0.f,0.f,0.f,0.f}, lc3 = {0.f,0.f,0.f,0.f};
    const f32x4 zc = {0.f,0.f,0.f,0.f};

    const _Float16* kp = K + (size_t)bh * NN * DD + (size_t)(kbase + col) * DD + quad * 4;
    const _Float16* vp = VT + (size_t)bh * DD * NN + (size_t)col * NN + kbase + quad * 4;

    f16x4 kfa = *(const f16x4*)(kp);
    f16x4 kfb = *(const f16x4*)(kp + 16 * DD);
    f16x4 vfa = *(const f16x4*)(vp);
    f16x4 vfb = *(const f16x4*)(vp + 16);

#define K2_CHUNK(KF, VF)                                                        \
    {                                                                           \
        f32x4 s0 = __builtin_amdgcn_mfma_f32_16x16x16f16(KF, qf0, zc, 0, 0, 0); \
        f32x4 s1 = __builtin_amdgcn_mfma_f32_16x16x16f16(KF, qf1, zc, 0, 0, 0); \
        f32x4 s2 = __builtin_amdgcn_mfma_f32_16x16x16f16(KF, qf2, zc, 0, 0, 0); \
        f32x4 s3 = __builtin_amdgcn_mfma_f32_16x16x16f16(KF, qf3, zc, 0, 0, 0); \
        hf2pair u0, u1, u2, u3;                                                 \
        u0.h[0] = __builtin_amdgcn_cvt_pkrtz(__builtin_amdgcn_exp2f(s0[0]),     \
                                             __builtin_amdgcn_exp2f(s0[1]));    \
        u0.h[1] = __builtin_amdgcn_cvt_pkrtz(__builtin_amdgcn_exp2f(s0[2]),     \
                                             __builtin_amdgcn_exp2f(s0[3]));    \
        u1.h[0] = __builtin_amdgcn_cvt_pkrtz(__builtin_amdgcn_exp2f(s1[0]),     \
                                             __builtin_amdgcn_exp2f(s1[1]));    \
        u1.h[1] = __builtin_amdgcn_cvt_pkrtz(__builtin_amdgcn_exp2f(s1[2]),     \
                                             __builtin_amdgcn_exp2f(s1[3]));    \
        u2.h[0] = __builtin_amdgcn_cvt_pkrtz(__builtin_amdgcn_exp2f(s2[0]),     \
                                             __builtin_amdgcn_exp2f(s2[1]));    \
        u2.h[1] = __builtin_amdgcn_cvt_pkrtz(__builtin_amdgcn_exp2f(s2[2]),     \
                                             __builtin_amdgcn_exp2f(s2[3]));    \
        u3.h[0] = __builtin_amdgcn_cvt_pkrtz(__builtin_amdgcn_exp2f(s3[0]),     \
                                             __builtin_amdgcn_exp2f(s3[1]));    \
        u3.h[1] = __builtin_amdgcn_cvt_pkrtz(__builtin_amdgcn_exp2f(s3[2]),     \
                                             __builtin_amdgcn_exp2f(s3[3]));    \
        f16x4 p0 = u0.v, p1 = u1.v, p2 = u2.v, p3 = u3.v;                       \
        lc0 = __builtin_amdgcn_mfma_f32_16x16x16f16(onesf, p0, lc0, 0, 0, 0);   \
        lc1 = __builtin_amdgcn_mfma_f32_16x16x16f16(onesf, p1, lc1, 0, 0, 0);   \
        lc2 = __builtin_amdgcn_mfma_f32_16x16x16f16(onesf, p2, lc2, 0, 0, 0);   \
        lc3 = __builtin_amdgcn_mfma_f32_16x16x16f16(onesf, p3, lc3, 0, 0, 0);   \
        oa0 = __builtin_amdgcn_mfma_f32_16x16x16f16(VF, p0, oa0, 0, 0, 0);      \
        oa1 = __builtin_amdgcn_mfma_f32_16x16x16f16(VF, p1, oa1, 0, 0, 0);      \
        oa2 = __builtin_amdgcn_mfma_f32_16x16x16f16(VF, p2, oa2, 0, 0, 0);      \
        oa3 = __builtin_amdgcn_mfma_f32_16x16x16f16(VF, p3, oa3, 0, 0, 0);      \
    }

    for (int g = 0; g < 9; ++g) {        // 9 groups x 32 keys = 288
        f16x4 kna, knb, vna, vnb;
        if (g < 8) {
            kna = *(const f16x4*)(kp + 32 * DD);
            knb = *(const f16x4*)(kp + 48 * DD);
            vna = *(const f16x4*)(vp + 32);
            vnb = *(const f16x4*)(vp + 48);
        }
        K2_CHUNK(kfa, vfa)
        K2_CHUNK(kfb, vfb)
        kfa = kna; kfb = knb; vfa = vna; vfb = vnb;
        kp += 32 * DD; vp += 32;
    }
#undef K2_CHUNK

    // lc rows are all identical = l[q=col] partial over this wave's keys.
#pragma unroll
    for (int r = 0; r < 4; ++r) {
        Osh[wave][quad * 4 + r][ 0 + col] = oa0[r];
        Osh[wave][quad * 4 + r][16 + col] = oa1[r];
        Osh[wave][quad * 4 + r][32 + col] = oa2[r];
        Osh[wave][quad * 4 + r][48 + col] = oa3[r];
    }
    float lv = (quad == 0) ? lc0[0] : (quad == 1) ? lc1[0] : (quad == 2) ? lc2[0] : lc3[0];
    Lsh[wave][quad * 16 + col] = lv;
    __syncthreads();

    int t = threadIdx.x;
    int q = t & 63, dg = t >> 6;          // dg in 0..7 -> d = dg*2, dg*2+1
    float l = 0.f;
#pragma unroll
    for (int w = 0; w < 8; ++w) l += Lsh[w][q];
    float inv = 1.0f / l;
    float o0 = 0.f, o1 = 0.f;
#pragma unroll
    for (int w = 0; w < 8; ++w) {
        o0 += Osh[w][dg * 2 + 0][q];
        o1 += Osh[w][dg * 2 + 1][q];
    }
    int b = bh >> 3, h = bh & 7;
    __bf16* dst = AO + (size_t)(b * NN + qbase + q) * TT + h * DD + dg * 2;
    dst[0] = (__bf16)(o0 * inv);
    dst[1] = (__bf16)(o1 * inv);
}

// ---------------------------------------------------------------------------
// Kernel 3: projection  out[b,c,n] = sum_t w_out[c,t] * AO[b,n,t]  (pre-BN fp32
// straight into d_out). w_out read fp32 directly, cvt in-register (R4 form).
// ---------------------------------------------------------------------------
__global__ __launch_bounds__(256) void k3_proj(
    const __bf16* __restrict__ AO, const float* __restrict__ wout,
    float* __restrict__ out)
{
    int cb = blockIdx.x, nt = blockIdx.y, b = blockIdx.z;
    int lane = threadIdx.x & 63, wave = threadIdx.x >> 6;
    int quad = lane >> 4, col = lane & 15;
    int n0 = nt * 64 + wave * 16, c0 = cb * 32;

    f32x4 acc0 = {0.f, 0.f, 0.f, 0.f};
    f32x4 acc1 = {0.f, 0.f, 0.f, 0.f};

    const __bf16* ab  = AO + (size_t)(b * NN + n0 + col) * TT + quad * 8;
    const float*  wb0 = wout + (size_t)(c0 + col) * TT + quad * 8;
    const float*  wb1 = wb0 + 16 * TT;
#pragma unroll
    for (int ks = 0; ks < 4; ks++) {
        bf16x8 a = *(const bf16x8*)(ab + ks * 32);
        f32x4 wA = *(const f32x4*)(wb0 + ks * 32);
        f32x4 wB = *(const f32x4*)(wb0 + ks * 32 + 4);
        f32x4 wC = *(const f32x4*)(wb1 + ks * 32);
        f32x4 wD = *(const f32x4*)(wb1 + ks * 32 + 4);
        bf16x8 w0, w1;
#pragma unroll
        for (int j = 0; j < 4; j++) {
            w0[j]     = (__bf16)wA[j];
            w0[j + 4] = (__bf16)wB[j];
            w1[j]     = (__bf16)wC[j];
            w1[j + 4] = (__bf16)wD[j];
        }
        acc0 = __builtin_amdgcn_mfma_f32_16x16x32_bf16(a, w0, acc0, 0, 0, 0);
        acc1 = __builtin_amdgcn_mfma_f32_16x16x32_bf16(a, w1, acc1, 0, 0, 0);
    }
#pragma unroll
    for (int s = 0; s < 2; s++) {
        int c = c0 + s * 16 + col;
        float* dst = out + (size_t)(b * CC + c) * NN + n0 + quad * 4;
        *(f32x4*)dst = (s == 0) ? acc0 : acc1;
    }
}

// ---------------------------------------------------------------------------
// Kernel 4: training-mode BatchNorm, in place on d_out. One block per channel.
// ---------------------------------------------------------------------------
__global__ __launch_bounds__(256) void k4_bn(
    float* __restrict__ out, const float* __restrict__ gamma,
    const float* __restrict__ beta)
{
    int c = blockIdx.x;
    int t = threadIdx.x;
    float vals[18];
    float s = 0.f, q = 0.f;
#pragma unroll
    for (int i = 0; i < 18; i++) {
        int j = i * 256 + t;          // 0..4607 over (b,n)
        int b = j / NN, n = j % NN;
        float v = out[(size_t)(b * CC + c) * NN + n];
        vals[i] = v; s += v; q += v * v;
    }
#pragma unroll
    for (int m = 1; m < 64; m <<= 1) { s += __shfl_xor(s, m); q += __shfl_xor(q, m); }
    __shared__ float rs[4], rq[4];
    int lane = t & 63, wave = t >> 6;
    if (lane == 0) { rs[wave] = s; rq[wave] = q; }
    __syncthreads();
    s = rs[0] + rs[1] + rs[2] + rs[3];
    q = rq[0] + rq[1] + rq[2] + rq[3];
    float mean = s * (1.0f / 4608.0f);
    float var = q * (1.0f / 4608.0f) - mean * mean;
    float sc = rsqrtf(var + 1e-5f) * gamma[c];
    float sh = beta[c] - mean * sc;
#pragma unroll
    for (int i = 0; i < 18; i++) {
        int j = i * 256 + t;
        int b = j / NN, n = j % NN;
        out[(size_t)(b * CC + c) * NN + n] = vals[i] * sc + sh;
    }
}

// ---------------------------------------------------------------------------
extern "C" void kernel_launch(void* const* d_in, const int* in_sizes, int n_in,
                              void* d_out, int out_size, void* d_ws, size_t ws_size,
                              hipStream_t stream) {
    const float* x     = (const float*)d_in[0];
    const float* wqkv  = (const float*)d_in[1];
    const float* temp  = (const float*)d_in[2];
    const float* wout  = (const float*)d_in[3];
    const float* gamma = (const float*)d_in[4];
    const float* beta  = (const float*)d_in[5];
    float* out = (float*)d_out;
    char* ws = (char*)d_ws;

    _Float16* Q  = (_Float16*)(ws + OFF_Q);
    _Float16* K  = (_Float16*)(ws + OFF_K);
    _Float16* VT = (_Float16*)(ws + OFF_VT);
    __bf16*   AO = (__bf16*)(ws + OFF_AO);

    k1_qkv<<<dim3(6, 36, 2), 256, 0, stream>>>(x, wqkv, Q, K, VT);
    k2_attn<<<dim3(36, 16), 512, 0, stream>>>(Q, K, VT, temp, AO);
    k3_proj<<<dim3(16, 36, 2), 256, 0, stream>>>(AO, wout, out);
    k4_bn<<<512, 256, 0, stream>>>(out, gamma, beta);
}